// Round 4
// baseline (289.802 us; speedup 1.0000x reference)
//
#include <hip/hip_runtime.h>
#include <cmath>

namespace {
constexpr int Hh = 224, Ww = 448;
constexpr int Tt = 2, Vv = 2, GH = 56, GW = 112;
constexpr int Nn = Vv * GH * GW;       // 12544 gaussians per (t) set, rendered in every view
constexpr int TV = Tt * Vv;            // 4 render views
constexpr int TOT = TV * Nn;           // 50176 (view,gaussian) pairs
constexpr int HW = Hh * Ww;            // 100352
constexpr int TILE = 16;
constexpr int NTX = Ww / TILE;         // 28
constexpr int NTY = Hh / TILE;         // 14
constexpr int NTILES = TV * NTX * NTY; // 1568
constexpr int CAP_T = 1024;            // per-tile list capacity (expected peak ~150)

constexpr size_t RGB_SZ = (size_t)TV * 3 * HW;   // 1204224
constexpr size_t AL_SZ  = (size_t)TV * HW;       // 401408
constexpr size_t OFF_RGB_STA = 0;
constexpr size_t OFF_RGB_DYN = RGB_SZ;
constexpr size_t OFF_RGB_ALL = 2 * RGB_SZ;
constexpr size_t OFF_AL_STA  = 3 * RGB_SZ;
constexpr size_t OFF_AL_DYN  = 3 * RGB_SZ + AL_SZ;
constexpr size_t OFF_AL_ALL  = 3 * RGB_SZ + 2 * AL_SZ;
constexpr size_t OFF_SEM     = 3 * RGB_SZ + 3 * AL_SZ;
constexpr size_t OFF_SM      = OFF_SEM + RGB_SZ;
constexpr size_t OFF_TOUCH   = OFF_SM + 1;

// ---- ws layout (floats) ----
// [0..10]*TOT : z, u, v, sig, pack(int), r, g, b, aAll, aDyn, aSta
// then        : 4 f sum_sigma | 4 i cnt | 4 i touch | 4 i done | NTILES i tcnt | lists
constexpr size_t WS_SUM  = (size_t)11 * TOT;
constexpr size_t WS_CNT  = WS_SUM + 4;
constexpr size_t WS_TCH  = WS_CNT + 4;
constexpr size_t WS_DONE = WS_TCH + 4;
constexpr size_t WS_TCNT = WS_DONE + 4;
constexpr size_t WS_LIST = WS_TCNT + NTILES;
constexpr int    N_ZERO  = (int)(WS_LIST - WS_SUM);  // ints to zero
} // namespace

__device__ inline unsigned long long shfl_xor_u64(unsigned long long x, int m) {
  unsigned int lo = (unsigned int)x, hi = (unsigned int)(x >> 32);
  lo = __shfl_xor(lo, m, 64);
  hi = __shfl_xor(hi, m, 64);
  return ((unsigned long long)hi << 32) | lo;
}

// sem copy + zero the counter region (independent of everything else; runs first)
__global__ __launch_bounds__(256) void init_k(const float4* __restrict__ sem,
                                              float4* __restrict__ dst,
                                              float* __restrict__ ws) {
  const int i = blockIdx.x * 256 + threadIdx.x;
  if (i < (int)(RGB_SZ / 4)) dst[i] = sem[i];
  if (blockIdx.x == gridDim.x - 1) {
    int* W = (int*)(ws + WS_SUM);
    for (int k = threadIdx.x; k < N_ZERO; k += 256) W[k] = 0;
  }
}

__global__ __launch_bounds__(256) void preprocess_k(
    const float* __restrict__ center, const float* __restrict__ scale,
    const float* __restrict__ feat, const float* __restrict__ opac,
    const float* __restrict__ bg, const float* __restrict__ intr,
    const float* __restrict__ fpose, const float* __restrict__ c2w,
    float* __restrict__ ws) {
#pragma clang fp contract(off)
  const int idx = blockIdx.x * 256 + threadIdx.x;
  // Nn = 12544 = 49*256, so tv is uniform across the block.
  const int n  = idx % Nn;
  const int tv = idx / Nn;
  const int v  = tv % Vv;
  const int t  = tv / Vv;
  const size_t gi = (size_t)t * Nn + n;   // gaussian params depend on (t,n) only

  float* Wz  = ws;
  float* Wu  = ws + (size_t)1 * TOT;
  float* Wvv = ws + (size_t)2 * TOT;
  float* Wsg = ws + (size_t)3 * TOT;
  int*   Wpk = (int*)(ws + (size_t)4 * TOT);
  float* Wr  = ws + (size_t)5 * TOT;
  float* Wg  = ws + (size_t)6 * TOT;
  float* Wb  = ws + (size_t)7 * TOT;
  float* Waa = ws + (size_t)8 * TOT;
  float* Wad = ws + (size_t)9 * TOT;
  float* Was = ws + (size_t)10 * TOT;
  float* Wsum = ws + WS_SUM;
  int*   Wcnt = (int*)(ws + WS_CNT);
  int*   Wtcnt = (int*)(ws + WS_TCNT);
  int*   Wlist = (int*)(ws + WS_LIST);

  // ---- w2c = inv(c2w[tv]) via fp64 adjugate (unrolled, register-resident).
  // For this data the rotation is exactly identity, so the result is exactly
  // [I | -t] — matches the fp32 reference inverse bitwise.
  double m00, m01, m02, m03, m10, m11, m12, m13,
         m20, m21, m22, m23, m30, m31, m32, m33;
  {
    const float* C = c2w + (size_t)tv * 16;
    m00 = C[0];  m01 = C[1];  m02 = C[2];  m03 = C[3];
    m10 = C[4];  m11 = C[5];  m12 = C[6];  m13 = C[7];
    m20 = C[8];  m21 = C[9];  m22 = C[10]; m23 = C[11];
    m30 = C[12]; m31 = C[13]; m32 = C[14]; m33 = C[15];
  }
  const double s0d = m00 * m11 - m10 * m01;
  const double s1d = m00 * m12 - m10 * m02;
  const double s2d = m00 * m13 - m10 * m03;
  const double s3d = m01 * m12 - m11 * m02;
  const double s4d = m01 * m13 - m11 * m03;
  const double s5d = m02 * m13 - m12 * m03;
  const double c5d = m22 * m33 - m32 * m23;
  const double c4d = m21 * m33 - m31 * m23;
  const double c3d = m21 * m32 - m31 * m22;
  const double c2d = m20 * m33 - m30 * m23;
  const double c1d = m20 * m32 - m30 * m22;
  const double c0d = m20 * m31 - m30 * m21;
  const double invdet =
      1.0 / (s0d * c5d - s1d * c4d + s2d * c3d + s3d * c2d - s4d * c1d + s5d * c0d);
  const float M0  = (float)(( m11 * c5d - m12 * c4d + m13 * c3d) * invdet);
  const float M1  = (float)((-m01 * c5d + m02 * c4d - m03 * c3d) * invdet);
  const float M2  = (float)(( m31 * s5d - m32 * s4d + m33 * s3d) * invdet);
  const float M3  = (float)((-m21 * s5d + m22 * s4d - m23 * s3d) * invdet);
  const float M4  = (float)((-m10 * c5d + m12 * c2d - m13 * c1d) * invdet);
  const float M5  = (float)(( m00 * c5d - m02 * c2d + m03 * c1d) * invdet);
  const float M6  = (float)((-m30 * s5d + m32 * s2d - m33 * s1d) * invdet);
  const float M7  = (float)(( m20 * s5d - m22 * s2d + m23 * s1d) * invdet);
  const float M8  = (float)(( m10 * c4d - m11 * c2d + m13 * c0d) * invdet);
  const float M9  = (float)((-m00 * c4d + m01 * c2d - m03 * c0d) * invdet);
  const float M10 = (float)(( m30 * s4d - m31 * s2d + m33 * s0d) * invdet);
  const float M11 = (float)((-m20 * s4d + m21 * s2d - m23 * s0d) * invdet);

  const float c0 = center[gi * 3 + 0], c1 = center[gi * 3 + 1], c2 = center[gi * 3 + 2];
  const float s0 = scale[gi * 3 + 0], s1 = scale[gi * 3 + 1], s2 = scale[gi * 3 + 2];
  const float sf = ((s0 + s1) + s2) / 3.0f;                 // jnp.mean(axis=-1)
  const float colr = fminf(fmaxf(feat[gi * 3 + 0], 0.0f), 1.0f);
  const float colg = fminf(fmaxf(feat[gi * 3 + 1], 0.0f), 1.0f);
  const float colb = fminf(fmaxf(feat[gi * 3 + 2], 0.0f), 1.0f);
  const float base = fminf(fmaxf(opac[gi], 0.0f), 1.0f);
  const float dyn  = fminf(fmaxf(1.0f - bg[gi], 0.0f), 1.0f);
  const float aAll = base;
  const float aDyn = base * dyn;           // <= aAll
  const float aSta = base * (1.0f - dyn);  // <= aAll

  // world = first_pose @ [c,1]  (exact when first_pose == I)
  float wd[4];
  for (int i = 0; i < 4; ++i)
    wd[i] = ((fpose[i * 4 + 0] * c0 + fpose[i * 4 + 1] * c1) + fpose[i * 4 + 2] * c2) +
            fpose[i * 4 + 3] * 1.0f;

  const float cam0 = ((M0 * wd[0] + M1 * wd[1]) + M2  * wd[2]) + M3  * wd[3];
  const float cam1 = ((M4 * wd[0] + M5 * wd[1]) + M6  * wd[2]) + M7  * wd[3];
  const float cam2 = ((M8 * wd[0] + M9 * wd[1]) + M10 * wd[2]) + M11 * wd[3];
  // finite iff |x| <= FLT_MAX (NaN compares false)
  const bool fin = (fabsf(cam0) <= 3.4028235e38f) && (fabsf(cam1) <= 3.4028235e38f) &&
                   (fabsf(cam2) <= 3.4028235e38f);
  const float z = cam2;
  const float fx = intr[v * 4 + 0], fy = intr[v * 4 + 1];
  const float ppx = intr[v * 4 + 2], ppy = intr[v * 4 + 3];

  bool kept = false;
  float u = 0.0f, vv2 = 0.0f, sig = 0.0f;
  if ((z > 0.001f) && fin) {
    u   = cam0 * fx / z + ppx;            // exact op sequence of the reference
    vv2 = cam1 * fy / z + ppy;
    float tsc = (fx + fy) * 0.5f;
    sig = tsc * fabsf(sf);
    sig = sig / fmaxf(z, 0.001f);
    sig = fminf(fmaxf(sig, 0.75f), 10.0f);
    const bool inb = (u >= -3.0f) && (u <= 450.0f) && (vv2 >= -3.0f) && (vv2 <= 226.0f);
    // aDyn,aSta <= aAll, so if aAll <= 1e-5 no branch keeps this gaussian.
    kept = inb && (aAll > 1e-5f);
  }

  if (kept) {
    Wz[idx] = z; Wu[idx] = u; Wvv[idx] = vv2; Wsg[idx] = sig;
    const int x0 = (int)floorf(u);
    const int y0 = (int)floorf(vv2);
    const float rc = ceilf(sig * 1.5f);   // RADIUS_SCALE
    const int rad = rc < 1.0f ? 1 : (rc > 2.0f ? 2 : (int)rc);
    Wpk[idx] = ((x0 + 4) << 16) | ((y0 + 4) << 4) | rad;
    Wr[idx] = colr; Wg[idx] = colg; Wb[idx] = colb;
    Waa[idx] = aAll; Wad[idx] = aDyn; Was[idx] = aSta;
    // ---- scatter binning: append n to every overlapped tile ----
    const int x_lo = x0 - rad, x_hi = x0 + rad;
    const int y_lo = y0 - rad, y_hi = y0 + rad;
    if (x_hi >= 0 && x_lo < Ww && y_hi >= 0 && y_lo < Hh) {
      const int tx_lo = (x_lo > 0 ? x_lo : 0) >> 4;
      const int tx_hi = (x_hi < Ww - 1 ? x_hi : Ww - 1) >> 4;
      const int ty_lo = (y_lo > 0 ? y_lo : 0) >> 4;
      const int ty_hi = (y_hi < Hh - 1 ? y_hi : Hh - 1) >> 4;
      for (int ty = ty_lo; ty <= ty_hi; ++ty)
        for (int tx = tx_lo; tx <= tx_hi; ++tx) {
          const int tile = (tv * NTY + ty) * NTX + tx;
          const int slot = atomicAdd(&Wtcnt[tile], 1);
          if (slot < CAP_T) Wlist[(size_t)tile * CAP_T + slot] = n;
        }
    }
  }

  // ---- sigma_mean reduction: wave shuffle -> LDS -> ONE atomic pair per block
  float sred = kept ? sig : 0.0f;
  int   cred = kept ? 1 : 0;
  #pragma unroll
  for (int off = 32; off > 0; off >>= 1) {
    sred += __shfl_down(sred, off, 64);
    cred += __shfl_down(cred, off, 64);
  }
  __shared__ float bsum[4];
  __shared__ int   bcnt[4];
  const int wv = threadIdx.x >> 6;
  if ((threadIdx.x & 63) == 0) { bsum[wv] = sred; bcnt[wv] = cred; }
  __syncthreads();
  if (threadIdx.x == 0) {
    const float ts = ((bsum[0] + bsum[1]) + bsum[2]) + bsum[3];
    const int   tc = bcnt[0] + bcnt[1] + bcnt[2] + bcnt[3];
    if (tc > 0) {
      atomicAdd(&Wsum[tv], ts);
      atomicAdd(&Wcnt[tv], tc);
    }
  }
}

__global__ __launch_bounds__(256) void raster_k(float* __restrict__ ws,
                                                float* __restrict__ out) {
#pragma clang fp contract(off)
  __shared__ unsigned long long s_key[CAP_T];
  __shared__ float s_u[256], s_v[256], s_sg[256];
  __shared__ float s_r[256], s_g[256], s_b[256];
  __shared__ float s_aa[256], s_ad[256], s_as[256];
  __shared__ int s_pk[256];

  const int tid = threadIdx.x;
  const int tv  = blockIdx.z;
  const int px  = blockIdx.x * TILE + (tid & 15);
  const int py  = blockIdx.y * TILE + (tid >> 4);
  const float fpx = (float)px, fpy = (float)py;
  const size_t base = (size_t)tv * Nn;

  const float* Wz  = ws;
  const float* Wu  = ws + (size_t)1 * TOT;
  const float* Wvv = ws + (size_t)2 * TOT;
  const float* Wsg = ws + (size_t)3 * TOT;
  const int*   Wpk = (const int*)(ws + (size_t)4 * TOT);
  const float* Wr  = ws + (size_t)5 * TOT;
  const float* Wg  = ws + (size_t)6 * TOT;
  const float* Wb  = ws + (size_t)7 * TOT;
  const float* Waa = ws + (size_t)8 * TOT;
  const float* Wad = ws + (size_t)9 * TOT;
  const float* Was = ws + (size_t)10 * TOT;
  float* Wsum = ws + WS_SUM;
  int*   Wcnt = (int*)(ws + WS_CNT);
  int*   Wtch = (int*)(ws + WS_TCH);
  int*   Wdone = (int*)(ws + WS_DONE);
  const int* Wtcnt = (const int*)(ws + WS_TCNT);
  const int* Wlist = (const int*)(ws + WS_LIST);

  const int tile = (tv * NTY + blockIdx.y) * NTX + blockIdx.x;
  const int cnt0 = Wtcnt[tile];
  const int cnt  = cnt0 < CAP_T ? cnt0 : CAP_T;
  const int* mylist = Wlist + (size_t)tile * CAP_T;

  // ---- sort by (z_bits, n): z>0 so float-bit order == value order; index
  // tiebreak replicates stable argsort ----
  if (cnt <= 256) {
    // fast path: one key per thread; shuffle compare-exchange for j<64
    // (intra-wave, no barrier), LDS round-trip only for j in {64,128}.
    unsigned long long key = ~0ULL;
    if (tid < cnt) {
      const unsigned int n = (unsigned int)mylist[tid];
      key = ((unsigned long long)__float_as_uint(Wz[base + n]) << 32) | n;
    }
    for (int k = 2; k <= 256; k <<= 1) {
      for (int j = k >> 1; j > 0; j >>= 1) {
        unsigned long long other;
        if (j < 64) {
          other = shfl_xor_u64(key, j);
        } else {
          s_key[tid] = key; __syncthreads();
          other = s_key[tid ^ j]; __syncthreads();
        }
        const bool up = ((tid & k) == 0);
        const bool keep_min = (up == ((tid & j) == 0));
        key = keep_min ? (key < other ? key : other) : (key > other ? key : other);
      }
    }
    s_key[tid] = key;
    __syncthreads();
  } else {
    // slow path (cnt in (256,1024]): classic LDS bitonic
    for (int i = tid; i < cnt; i += 256) {
      const unsigned int n = (unsigned int)mylist[i];
      s_key[i] = ((unsigned long long)__float_as_uint(Wz[base + n]) << 32) | n;
    }
    int P = 1;
    while (P < cnt) P <<= 1;
    for (int i = cnt + tid; i < P; i += 256) s_key[i] = ~0ULL;
    __syncthreads();
    for (int k = 2; k <= P; k <<= 1) {
      for (int j = k >> 1; j > 0; j >>= 1) {
        for (int i = tid; i < P; i += 256) {
          const int ixj = i ^ j;
          if (ixj > i) {
            const unsigned long long a = s_key[i], b2 = s_key[ixj];
            const bool up = ((i & k) == 0);
            if ((a > b2) == up) { s_key[i] = b2; s_key[ixj] = a; }
          }
        }
        __syncthreads();
      }
    }
  }

  // ---- per-pixel front-to-back composite, 3 branches, chunked LDS staging ----
  float Aall = 0.0f, Adyn = 0.0f, Asta = 0.0f;
  float Ra = 0.0f, Ga = 0.0f, Ba = 0.0f;
  float Rd = 0.0f, Gd = 0.0f, Bd = 0.0f;
  float Rs = 0.0f, Gs = 0.0f, Bs = 0.0f;

  for (int cb = 0; cb < cnt; cb += 256) {
    const int m = min(256, cnt - cb);
    if (tid < m) {
      const int n = (int)(s_key[cb + tid] & 0xffffffffULL);
      const size_t a = base + (size_t)n;
      s_u[tid] = Wu[a]; s_v[tid] = Wvv[a]; s_sg[tid] = Wsg[a]; s_pk[tid] = Wpk[a];
      s_r[tid] = Wr[a]; s_g[tid] = Wg[a]; s_b[tid] = Wb[a];
      s_aa[tid] = Waa[a]; s_ad[tid] = Wad[a]; s_as[tid] = Was[a];
    }
    __syncthreads();
    for (int j = 0; j < m; ++j) {
      const int pk  = s_pk[j];
      const int rad = pk & 15;
      const int y0  = ((pk >> 4) & 0xfff) - 4;
      const int x0  = (pk >> 16) - 4;
      if (abs(px - x0) <= rad && abs(py - y0) <= rad) {
        const float sg = s_sg[j];
        const float du = (s_u[j] - fpx) / sg;
        const float dv = (s_v[j] - fpy) / sg;
        const float gs = expf(-0.5f * (du * du + dv * dv));
        {  // "all" branch: list membership already implies aAll > 1e-5
          const float la = fminf(fmaxf(gs * s_aa[j], 0.0f), 0.999f);
          const float tr = fminf(fmaxf(1.0f - Aall, 0.0f), 1.0f);
          const float ct = la * tr;
          Ra += s_r[j] * ct; Ga += s_g[j] * ct; Ba += s_b[j] * ct;
          Aall = fminf(fmaxf(Aall + ct, 0.0f), 0.999f);
        }
        const float ad = s_ad[j];
        if (ad > 1e-5f) {
          const float la = fminf(fmaxf(gs * ad, 0.0f), 0.999f);
          const float tr = fminf(fmaxf(1.0f - Adyn, 0.0f), 1.0f);
          const float ct = la * tr;
          Rd += s_r[j] * ct; Gd += s_g[j] * ct; Bd += s_b[j] * ct;
          Adyn = fminf(fmaxf(Adyn + ct, 0.0f), 0.999f);
        }
        const float as = s_as[j];
        if (as > 1e-5f) {
          const float la = fminf(fmaxf(gs * as, 0.0f), 0.999f);
          const float tr = fminf(fmaxf(1.0f - Asta, 0.0f), 1.0f);
          const float ct = la * tr;
          Rs += s_r[j] * ct; Gs += s_g[j] * ct; Bs += s_b[j] * ct;
          Asta = fminf(fmaxf(Asta + ct, 0.0f), 0.999f);
        }
      }
    }
    __syncthreads();
  }

  // ---- write outputs ----
  const size_t pix = (size_t)py * Ww + px;
  const size_t hw  = (size_t)HW;
  const size_t m3  = (size_t)tv * 3;
  out[OFF_RGB_STA + (m3 + 0) * hw + pix] = fminf(fmaxf(Rs, 0.0f), 1.0f);
  out[OFF_RGB_STA + (m3 + 1) * hw + pix] = fminf(fmaxf(Gs, 0.0f), 1.0f);
  out[OFF_RGB_STA + (m3 + 2) * hw + pix] = fminf(fmaxf(Bs, 0.0f), 1.0f);
  out[OFF_RGB_DYN + (m3 + 0) * hw + pix] = fminf(fmaxf(Rd, 0.0f), 1.0f);
  out[OFF_RGB_DYN + (m3 + 1) * hw + pix] = fminf(fmaxf(Gd, 0.0f), 1.0f);
  out[OFF_RGB_DYN + (m3 + 2) * hw + pix] = fminf(fmaxf(Bd, 0.0f), 1.0f);
  out[OFF_RGB_ALL + (m3 + 0) * hw + pix] = fminf(fmaxf(Ra, 0.0f), 1.0f);
  out[OFF_RGB_ALL + (m3 + 1) * hw + pix] = fminf(fmaxf(Ga, 0.0f), 1.0f);
  out[OFF_RGB_ALL + (m3 + 2) * hw + pix] = fminf(fmaxf(Ba, 0.0f), 1.0f);
  out[OFF_AL_STA + (size_t)tv * hw + pix] = fminf(fmaxf(Asta, 0.0f), 1.0f);
  out[OFF_AL_DYN + (size_t)tv * hw + pix] = fminf(fmaxf(Adyn, 0.0f), 1.0f);
  out[OFF_AL_ALL + (size_t)tv * hw + pix] = fminf(fmaxf(Aall, 0.0f), 1.0f);

  // touch: count pixels with Aall > 1e-6 (one atomic per wave)
  const unsigned long long bal = __ballot(Aall > 1e-6f);
  if ((tid & 63) == 0) atomicAdd(&Wtch[tv], (int)__popcll(bal));

  // ---- inline finalize: last block computes sigma_mean / touch ----
  __threadfence();
  if (tid == 0) {
    const int prev = atomicAdd(Wdone, 1);
    if (prev == NTILES - 1) {
      float sm = 0.0f, th = 0.0f;
      for (int i = 0; i < TV; ++i) {
        const int c = Wcnt[i];                    // written by previous kernel
        sm += (c > 0) ? (Wsum[i] / (float)(c > 1 ? c : 1)) : 0.0f;
        const int tch = atomicAdd(&Wtch[i], 0);   // device-coherent read
        th += (float)tch / (float)HW;
      }
      out[OFF_SM]    = sm / (float)TV;
      out[OFF_TOUCH] = th / (float)TV;
    }
  }
}

extern "C" void kernel_launch(void* const* d_in, const int* in_sizes, int n_in,
                              void* d_out, int out_size, void* d_ws, size_t ws_size,
                              hipStream_t stream) {
  const float* center = (const float*)d_in[0];
  const float* scale  = (const float*)d_in[1];
  const float* feat   = (const float*)d_in[2];
  const float* opac   = (const float*)d_in[3];
  const float* bg     = (const float*)d_in[4];
  const float* sem    = (const float*)d_in[5];
  const float* intr   = (const float*)d_in[6];
  const float* c2w    = (const float*)d_in[7];
  const float* fpose  = (const float*)d_in[8];
  float* out = (float*)d_out;
  float* ws  = (float*)d_ws;

  const int copy_blocks = (int)((RGB_SZ / 4 + 255) / 256) + 1;  // last block zeroes
  hipLaunchKernelGGL(init_k, dim3(copy_blocks), dim3(256), 0, stream,
                     (const float4*)sem, (float4*)(out + OFF_SEM), ws);
  hipLaunchKernelGGL(preprocess_k, dim3(TOT / 256), dim3(256), 0, stream,
                     center, scale, feat, opac, bg, intr, fpose, c2w, ws);
  hipLaunchKernelGGL(raster_k, dim3(NTX, NTY, TV), dim3(256), 0, stream, ws, out);
}

// Round 5
// 129.677 us; speedup vs baseline: 2.2348x; 2.2348x over previous
//
#include <hip/hip_runtime.h>
#include <cmath>

namespace {
constexpr int Hh = 224, Ww = 448;
constexpr int Tt = 2, Vv = 2, GH = 56, GW = 112;
constexpr int Nn = Vv * GH * GW;       // 12544 gaussians per (t) set
constexpr int TV = Tt * Vv;            // 4 render views
constexpr int TOT = TV * Nn;           // 50176 (view,gaussian) pairs
constexpr int HW = Hh * Ww;            // 100352
constexpr int TILE = 8;                // 8x8 tiles, one wave per tile
constexpr int NTX = Ww / TILE;         // 56
constexpr int NTY = Hh / TILE;         // 28
constexpr int NTILES = TV * NTX * NTY; // 6272
constexpr int CAP_T = 256;             // per-tile list capacity (expected peak ~80)

constexpr size_t RGB_SZ = (size_t)TV * 3 * HW;   // 1204224
constexpr size_t AL_SZ  = (size_t)TV * HW;       // 401408
constexpr size_t OFF_RGB_STA = 0;
constexpr size_t OFF_RGB_DYN = RGB_SZ;
constexpr size_t OFF_RGB_ALL = 2 * RGB_SZ;
constexpr size_t OFF_AL_STA  = 3 * RGB_SZ;
constexpr size_t OFF_AL_DYN  = 3 * RGB_SZ + AL_SZ;
constexpr size_t OFF_AL_ALL  = 3 * RGB_SZ + 2 * AL_SZ;
constexpr size_t OFF_SEM     = 3 * RGB_SZ + 3 * AL_SZ;
constexpr size_t OFF_SM      = OFF_SEM + RGB_SZ;
constexpr size_t OFF_TOUCH   = OFF_SM + 1;

// ---- ws layout (floats) ----
// [0..10]*TOT : z, u, v, sig, pack(int), r, g, b, aAll, aDyn, aSta
// then: 4 f sum_sigma | 4 i cnt | NTILES i tile-counters | NTILES i per-tile
// touch | NTILES*CAP_T i tile lists
constexpr size_t WS_SUM  = (size_t)11 * TOT;
constexpr size_t WS_CNT  = WS_SUM + 4;
constexpr size_t WS_TCNT = WS_CNT + 4;
constexpr size_t WS_TPB  = WS_TCNT + NTILES;
constexpr size_t WS_LIST = WS_TPB + NTILES;
constexpr int    N_ZERO  = 8 + NTILES;  // Wsum+Wcnt+Wtcnt (touch needs no zero)
} // namespace

__device__ inline unsigned long long shfl_xor_u64(unsigned long long x, int m) {
  unsigned int lo = (unsigned int)x, hi = (unsigned int)(x >> 32);
  lo = __shfl_xor(lo, m, 64);
  hi = __shfl_xor(hi, m, 64);
  return ((unsigned long long)hi << 32) | lo;
}

// sem copy + zero the counter region
__global__ __launch_bounds__(256) void init_k(const float4* __restrict__ sem,
                                              float4* __restrict__ dst,
                                              float* __restrict__ ws) {
  const int i = blockIdx.x * 256 + threadIdx.x;
  if (i < (int)(RGB_SZ / 4)) dst[i] = sem[i];
  if (blockIdx.x == gridDim.x - 1) {
    int* W = (int*)(ws + WS_SUM);
    for (int k = threadIdx.x; k < N_ZERO; k += 256) W[k] = 0;
  }
}

__global__ __launch_bounds__(256) void preprocess_k(
    const float* __restrict__ center, const float* __restrict__ scale,
    const float* __restrict__ feat, const float* __restrict__ opac,
    const float* __restrict__ bg, const float* __restrict__ intr,
    const float* __restrict__ fpose, const float* __restrict__ c2w,
    float* __restrict__ ws) {
#pragma clang fp contract(off)
  const int idx = blockIdx.x * 256 + threadIdx.x;
  // Nn = 12544 = 49*256, so tv is uniform across the block.
  const int n  = idx % Nn;
  const int tv = idx / Nn;
  const int v  = tv % Vv;
  const int t  = tv / Vv;
  const size_t gi = (size_t)t * Nn + n;   // gaussian params depend on (t,n) only

  float* Wz  = ws;
  float* Wu  = ws + (size_t)1 * TOT;
  float* Wvv = ws + (size_t)2 * TOT;
  float* Wsg = ws + (size_t)3 * TOT;
  int*   Wpk = (int*)(ws + (size_t)4 * TOT);
  float* Wr  = ws + (size_t)5 * TOT;
  float* Wg  = ws + (size_t)6 * TOT;
  float* Wb  = ws + (size_t)7 * TOT;
  float* Waa = ws + (size_t)8 * TOT;
  float* Wad = ws + (size_t)9 * TOT;
  float* Was = ws + (size_t)10 * TOT;
  float* Wsum = ws + WS_SUM;
  int*   Wcnt = (int*)(ws + WS_CNT);
  int*   Wtcnt = (int*)(ws + WS_TCNT);
  int*   Wlist = (int*)(ws + WS_LIST);

  // ---- w2c = inv(c2w[tv]) via fp64 adjugate (unrolled, register-resident).
  // Rotation is exactly identity here, so the result is exactly [I | -t] —
  // matches the fp32 reference inverse bitwise.
  double m00, m01, m02, m03, m10, m11, m12, m13,
         m20, m21, m22, m23, m30, m31, m32, m33;
  {
    const float* C = c2w + (size_t)tv * 16;
    m00 = C[0];  m01 = C[1];  m02 = C[2];  m03 = C[3];
    m10 = C[4];  m11 = C[5];  m12 = C[6];  m13 = C[7];
    m20 = C[8];  m21 = C[9];  m22 = C[10]; m23 = C[11];
    m30 = C[12]; m31 = C[13]; m32 = C[14]; m33 = C[15];
  }
  const double s0d = m00 * m11 - m10 * m01;
  const double s1d = m00 * m12 - m10 * m02;
  const double s2d = m00 * m13 - m10 * m03;
  const double s3d = m01 * m12 - m11 * m02;
  const double s4d = m01 * m13 - m11 * m03;
  const double s5d = m02 * m13 - m12 * m03;
  const double c5d = m22 * m33 - m32 * m23;
  const double c4d = m21 * m33 - m31 * m23;
  const double c3d = m21 * m32 - m31 * m22;
  const double c2d = m20 * m33 - m30 * m23;
  const double c1d = m20 * m32 - m30 * m22;
  const double c0d = m20 * m31 - m30 * m21;
  const double invdet =
      1.0 / (s0d * c5d - s1d * c4d + s2d * c3d + s3d * c2d - s4d * c1d + s5d * c0d);
  const float M0  = (float)(( m11 * c5d - m12 * c4d + m13 * c3d) * invdet);
  const float M1  = (float)((-m01 * c5d + m02 * c4d - m03 * c3d) * invdet);
  const float M2  = (float)(( m31 * s5d - m32 * s4d + m33 * s3d) * invdet);
  const float M3  = (float)((-m21 * s5d + m22 * s4d - m23 * s3d) * invdet);
  const float M4  = (float)((-m10 * c5d + m12 * c2d - m13 * c1d) * invdet);
  const float M5  = (float)(( m00 * c5d - m02 * c2d + m03 * c1d) * invdet);
  const float M6  = (float)((-m30 * s5d + m32 * s2d - m33 * s1d) * invdet);
  const float M7  = (float)(( m20 * s5d - m22 * s2d + m23 * s1d) * invdet);
  const float M8  = (float)(( m10 * c4d - m11 * c2d + m13 * c0d) * invdet);
  const float M9  = (float)((-m00 * c4d + m01 * c2d - m03 * c0d) * invdet);
  const float M10 = (float)(( m30 * s4d - m31 * s2d + m33 * s0d) * invdet);
  const float M11 = (float)((-m20 * s4d + m21 * s2d - m23 * s0d) * invdet);

  const float c0 = center[gi * 3 + 0], c1 = center[gi * 3 + 1], c2 = center[gi * 3 + 2];
  const float s0 = scale[gi * 3 + 0], s1 = scale[gi * 3 + 1], s2 = scale[gi * 3 + 2];
  const float sf = ((s0 + s1) + s2) / 3.0f;                 // jnp.mean(axis=-1)
  const float colr = fminf(fmaxf(feat[gi * 3 + 0], 0.0f), 1.0f);
  const float colg = fminf(fmaxf(feat[gi * 3 + 1], 0.0f), 1.0f);
  const float colb = fminf(fmaxf(feat[gi * 3 + 2], 0.0f), 1.0f);
  const float base = fminf(fmaxf(opac[gi], 0.0f), 1.0f);
  const float dyn  = fminf(fmaxf(1.0f - bg[gi], 0.0f), 1.0f);
  const float aAll = base;
  const float aDyn = base * dyn;           // <= aAll
  const float aSta = base * (1.0f - dyn);  // <= aAll

  // world = first_pose @ [c,1]  (exact when first_pose == I)
  float wd[4];
  for (int i = 0; i < 4; ++i)
    wd[i] = ((fpose[i * 4 + 0] * c0 + fpose[i * 4 + 1] * c1) + fpose[i * 4 + 2] * c2) +
            fpose[i * 4 + 3] * 1.0f;

  const float cam0 = ((M0 * wd[0] + M1 * wd[1]) + M2  * wd[2]) + M3  * wd[3];
  const float cam1 = ((M4 * wd[0] + M5 * wd[1]) + M6  * wd[2]) + M7  * wd[3];
  const float cam2 = ((M8 * wd[0] + M9 * wd[1]) + M10 * wd[2]) + M11 * wd[3];
  const bool fin = (fabsf(cam0) <= 3.4028235e38f) && (fabsf(cam1) <= 3.4028235e38f) &&
                   (fabsf(cam2) <= 3.4028235e38f);
  const float z = cam2;
  const float fx = intr[v * 4 + 0], fy = intr[v * 4 + 1];
  const float ppx = intr[v * 4 + 2], ppy = intr[v * 4 + 3];

  bool kept = false;
  float u = 0.0f, vv2 = 0.0f, sig = 0.0f;
  if ((z > 0.001f) && fin) {
    u   = cam0 * fx / z + ppx;            // exact op sequence of the reference
    vv2 = cam1 * fy / z + ppy;
    float tsc = (fx + fy) * 0.5f;
    sig = tsc * fabsf(sf);
    sig = sig / fmaxf(z, 0.001f);
    sig = fminf(fmaxf(sig, 0.75f), 10.0f);
    const bool inb = (u >= -3.0f) && (u <= 450.0f) && (vv2 >= -3.0f) && (vv2 <= 226.0f);
    kept = inb && (aAll > 1e-5f);
  }

  if (kept) {
    Wz[idx] = z; Wu[idx] = u; Wvv[idx] = vv2; Wsg[idx] = sig;
    const int x0 = (int)floorf(u);
    const int y0 = (int)floorf(vv2);
    const float rc = ceilf(sig * 1.5f);   // RADIUS_SCALE
    const int rad = rc < 1.0f ? 1 : (rc > 2.0f ? 2 : (int)rc);
    Wpk[idx] = ((x0 + 4) << 16) | ((y0 + 4) << 4) | rad;
    Wr[idx] = colr; Wg[idx] = colg; Wb[idx] = colb;
    Waa[idx] = aAll; Wad[idx] = aDyn; Was[idx] = aSta;
    // ---- scatter binning to 8x8 tiles (bbox interval-overlap) ----
    const int x_lo = x0 - rad, x_hi = x0 + rad;
    const int y_lo = y0 - rad, y_hi = y0 + rad;
    if (x_hi >= 0 && x_lo < Ww && y_hi >= 0 && y_lo < Hh) {
      const int tx_lo = (x_lo > 0 ? x_lo : 0) >> 3;
      const int tx_hi = (x_hi < Ww - 1 ? x_hi : Ww - 1) >> 3;
      const int ty_lo = (y_lo > 0 ? y_lo : 0) >> 3;
      const int ty_hi = (y_hi < Hh - 1 ? y_hi : Hh - 1) >> 3;
      for (int ty = ty_lo; ty <= ty_hi; ++ty)
        for (int tx = tx_lo; tx <= tx_hi; ++tx) {
          const int tile = (tv * NTY + ty) * NTX + tx;
          const int slot = atomicAdd(&Wtcnt[tile], 1);
          if (slot < CAP_T) Wlist[(size_t)tile * CAP_T + slot] = n;
        }
    }
  }

  // ---- sigma_mean reduction: wave shuffle -> LDS -> ONE atomic pair per block
  float sred = kept ? sig : 0.0f;
  int   cred = kept ? 1 : 0;
  #pragma unroll
  for (int off = 32; off > 0; off >>= 1) {
    sred += __shfl_down(sred, off, 64);
    cred += __shfl_down(cred, off, 64);
  }
  __shared__ float bsum[4];
  __shared__ int   bcnt[4];
  const int wv = threadIdx.x >> 6;
  if ((threadIdx.x & 63) == 0) { bsum[wv] = sred; bcnt[wv] = cred; }
  __syncthreads();
  if (threadIdx.x == 0) {
    const float ts = ((bsum[0] + bsum[1]) + bsum[2]) + bsum[3];
    const int   tc = bcnt[0] + bcnt[1] + bcnt[2] + bcnt[3];
    if (tc > 0) {
      atomicAdd(&Wsum[tv], ts);
      atomicAdd(&Wcnt[tv], tc);
    }
  }
}

// One wave (64 threads) per 8x8 tile. Single-wave blocks: __syncthreads is
// effectively free, and the cnt<=64 sort is a pure in-register shuffle bitonic.
__global__ __launch_bounds__(64) void raster_k(float* __restrict__ ws,
                                               float* __restrict__ out) {
#pragma clang fp contract(off)
  __shared__ unsigned long long s_key[CAP_T];
  __shared__ float s_u[64], s_v[64], s_sg[64];
  __shared__ float s_r[64], s_g[64], s_b[64];
  __shared__ float s_aa[64], s_ad[64], s_as[64];
  __shared__ int s_pk[64];

  const int tid = threadIdx.x;   // 0..63
  const int tv  = blockIdx.z;
  const int px  = blockIdx.x * TILE + (tid & 7);
  const int py  = blockIdx.y * TILE + (tid >> 3);
  const float fpx = (float)px, fpy = (float)py;
  const size_t base = (size_t)tv * Nn;

  const float* Wz  = ws;
  const float* Wu  = ws + (size_t)1 * TOT;
  const float* Wvv = ws + (size_t)2 * TOT;
  const float* Wsg = ws + (size_t)3 * TOT;
  const int*   Wpk = (const int*)(ws + (size_t)4 * TOT);
  const float* Wr  = ws + (size_t)5 * TOT;
  const float* Wg  = ws + (size_t)6 * TOT;
  const float* Wb  = ws + (size_t)7 * TOT;
  const float* Waa = ws + (size_t)8 * TOT;
  const float* Wad = ws + (size_t)9 * TOT;
  const float* Was = ws + (size_t)10 * TOT;
  int*       Wtpb  = (int*)(ws + WS_TPB);
  const int* Wtcnt = (const int*)(ws + WS_TCNT);
  const int* Wlist = (const int*)(ws + WS_LIST);

  const int tile = (tv * NTY + blockIdx.y) * NTX + blockIdx.x;
  const int cnt0 = Wtcnt[tile];
  const int cnt  = cnt0 < CAP_T ? cnt0 : CAP_T;
  const int* mylist = Wlist + (size_t)tile * CAP_T;

  float Aall = 0.0f, Adyn = 0.0f, Asta = 0.0f;
  float Ra = 0.0f, Ga = 0.0f, Ba = 0.0f;
  float Rd = 0.0f, Gd = 0.0f, Bd = 0.0f;
  float Rs = 0.0f, Gs = 0.0f, Bs = 0.0f;

  auto composite = [&](int m) {
    for (int j = 0; j < m; ++j) {
      const int pk  = s_pk[j];
      const int rad = pk & 15;
      const int y0  = ((pk >> 4) & 0xfff) - 4;
      const int x0  = (pk >> 16) - 4;
      if (abs(px - x0) <= rad && abs(py - y0) <= rad) {
        const float sg = s_sg[j];
        const float du = (s_u[j] - fpx) / sg;
        const float dv = (s_v[j] - fpy) / sg;
        const float gs = expf(-0.5f * (du * du + dv * dv));
        {  // "all" branch: list membership implies aAll > 1e-5
          const float la = fminf(fmaxf(gs * s_aa[j], 0.0f), 0.999f);
          const float tr = fminf(fmaxf(1.0f - Aall, 0.0f), 1.0f);
          const float ct = la * tr;
          Ra += s_r[j] * ct; Ga += s_g[j] * ct; Ba += s_b[j] * ct;
          Aall = fminf(fmaxf(Aall + ct, 0.0f), 0.999f);
        }
        const float ad = s_ad[j];
        if (ad > 1e-5f) {
          const float la = fminf(fmaxf(gs * ad, 0.0f), 0.999f);
          const float tr = fminf(fmaxf(1.0f - Adyn, 0.0f), 1.0f);
          const float ct = la * tr;
          Rd += s_r[j] * ct; Gd += s_g[j] * ct; Bd += s_b[j] * ct;
          Adyn = fminf(fmaxf(Adyn + ct, 0.0f), 0.999f);
        }
        const float as = s_as[j];
        if (as > 1e-5f) {
          const float la = fminf(fmaxf(gs * as, 0.0f), 0.999f);
          const float tr = fminf(fmaxf(1.0f - Asta, 0.0f), 1.0f);
          const float ct = la * tr;
          Rs += s_r[j] * ct; Gs += s_g[j] * ct; Bs += s_b[j] * ct;
          Asta = fminf(fmaxf(Asta + ct, 0.0f), 0.999f);
        }
      }
    }
  };

  if (cnt <= 64) {
    // ---- in-register wave bitonic on (z_bits, n): no LDS, no barriers.
    // z>0 so float-bit order == value order; index tiebreak == stable argsort.
    unsigned long long key = ~0ULL;
    if (tid < cnt) {
      const unsigned int n = (unsigned int)mylist[tid];
      key = ((unsigned long long)__float_as_uint(Wz[base + n]) << 32) | n;
    }
    if (cnt > 1) {
      for (int k = 2; k <= 64; k <<= 1) {
        for (int j = k >> 1; j > 0; j >>= 1) {
          const unsigned long long other = shfl_xor_u64(key, j);
          const bool up = ((tid & k) == 0);
          const bool keep_min = (up == ((tid & j) == 0));
          key = keep_min ? (key < other ? key : other) : (key > other ? key : other);
        }
      }
    }
    if (tid < cnt) {  // lane tid holds rank-tid entry; stage it
      const int n = (int)(key & 0xffffffffULL);
      const size_t a = base + (size_t)n;
      s_u[tid] = Wu[a]; s_v[tid] = Wvv[a]; s_sg[tid] = Wsg[a]; s_pk[tid] = Wpk[a];
      s_r[tid] = Wr[a]; s_g[tid] = Wg[a]; s_b[tid] = Wb[a];
      s_aa[tid] = Waa[a]; s_ad[tid] = Wad[a]; s_as[tid] = Was[a];
    }
    __syncthreads();   // single wave: near-free, orders LDS writes->reads
    composite(cnt);
  } else {
    // ---- LDS bitonic over P = next pow2 (<= 256), 64 threads striding ----
    for (int i = tid; i < cnt; i += 64) {
      const unsigned int n = (unsigned int)mylist[i];
      s_key[i] = ((unsigned long long)__float_as_uint(Wz[base + n]) << 32) | n;
    }
    int P = 1;
    while (P < cnt) P <<= 1;
    for (int i = cnt + tid; i < P; i += 64) s_key[i] = ~0ULL;
    __syncthreads();
    for (int k = 2; k <= P; k <<= 1) {
      for (int j = k >> 1; j > 0; j >>= 1) {
        for (int i = tid; i < P; i += 64) {
          const int ixj = i ^ j;
          if (ixj > i) {
            const unsigned long long a = s_key[i], b2 = s_key[ixj];
            const bool up = ((i & k) == 0);
            if ((a > b2) == up) { s_key[i] = b2; s_key[ixj] = a; }
          }
        }
        __syncthreads();
      }
    }
    for (int cb = 0; cb < cnt; cb += 64) {
      const int m = min(64, cnt - cb);
      if (tid < m) {
        const int n = (int)(s_key[cb + tid] & 0xffffffffULL);
        const size_t a = base + (size_t)n;
        s_u[tid] = Wu[a]; s_v[tid] = Wvv[a]; s_sg[tid] = Wsg[a]; s_pk[tid] = Wpk[a];
        s_r[tid] = Wr[a]; s_g[tid] = Wg[a]; s_b[tid] = Wb[a];
        s_aa[tid] = Waa[a]; s_ad[tid] = Wad[a]; s_as[tid] = Was[a];
      }
      __syncthreads();
      composite(m);
      __syncthreads();
    }
  }

  // ---- write outputs ----
  const size_t pix = (size_t)py * Ww + px;
  const size_t hw  = (size_t)HW;
  const size_t m3  = (size_t)tv * 3;
  out[OFF_RGB_STA + (m3 + 0) * hw + pix] = fminf(fmaxf(Rs, 0.0f), 1.0f);
  out[OFF_RGB_STA + (m3 + 1) * hw + pix] = fminf(fmaxf(Gs, 0.0f), 1.0f);
  out[OFF_RGB_STA + (m3 + 2) * hw + pix] = fminf(fmaxf(Bs, 0.0f), 1.0f);
  out[OFF_RGB_DYN + (m3 + 0) * hw + pix] = fminf(fmaxf(Rd, 0.0f), 1.0f);
  out[OFF_RGB_DYN + (m3 + 1) * hw + pix] = fminf(fmaxf(Gd, 0.0f), 1.0f);
  out[OFF_RGB_DYN + (m3 + 2) * hw + pix] = fminf(fmaxf(Bd, 0.0f), 1.0f);
  out[OFF_RGB_ALL + (m3 + 0) * hw + pix] = fminf(fmaxf(Ra, 0.0f), 1.0f);
  out[OFF_RGB_ALL + (m3 + 1) * hw + pix] = fminf(fmaxf(Ga, 0.0f), 1.0f);
  out[OFF_RGB_ALL + (m3 + 2) * hw + pix] = fminf(fmaxf(Ba, 0.0f), 1.0f);
  out[OFF_AL_STA + (size_t)tv * hw + pix] = fminf(fmaxf(Asta, 0.0f), 1.0f);
  out[OFF_AL_DYN + (size_t)tv * hw + pix] = fminf(fmaxf(Adyn, 0.0f), 1.0f);
  out[OFF_AL_ALL + (size_t)tv * hw + pix] = fminf(fmaxf(Aall, 0.0f), 1.0f);

  // per-tile touch count: plain store, no atomics
  const unsigned long long bal = __ballot(Aall > 1e-6f);
  if (tid == 0) Wtpb[tile] = (int)__popcll(bal);
}

__global__ __launch_bounds__(256) void finalize_k(const float* __restrict__ ws,
                                                  float* __restrict__ out) {
  const int tid = threadIdx.x;
  const int* Wtpb = (const int*)(ws + WS_TPB);
  // touch: mean over views of (count/HW) == grand_total / (HW*TV)
  int acc = 0;
  for (int i = tid; i < NTILES; i += 256) acc += Wtpb[i];
  #pragma unroll
  for (int off = 32; off > 0; off >>= 1) acc += __shfl_down(acc, off, 64);
  __shared__ int wsum[4];
  if ((tid & 63) == 0) wsum[tid >> 6] = acc;
  __syncthreads();
  if (tid == 0) {
    const int grand = wsum[0] + wsum[1] + wsum[2] + wsum[3];
    const float* Wsum = ws + WS_SUM;
    const int*   Wcnt = (const int*)(ws + WS_CNT);
    float sm = 0.0f;
    for (int i = 0; i < TV; ++i) {
      const int c = Wcnt[i];
      sm += (c > 0) ? (Wsum[i] / (float)(c > 1 ? c : 1)) : 0.0f;
    }
    out[OFF_SM]    = sm / (float)TV;
    out[OFF_TOUCH] = (float)grand / (float)(HW * TV);
  }
}

extern "C" void kernel_launch(void* const* d_in, const int* in_sizes, int n_in,
                              void* d_out, int out_size, void* d_ws, size_t ws_size,
                              hipStream_t stream) {
  const float* center = (const float*)d_in[0];
  const float* scale  = (const float*)d_in[1];
  const float* feat   = (const float*)d_in[2];
  const float* opac   = (const float*)d_in[3];
  const float* bg     = (const float*)d_in[4];
  const float* sem    = (const float*)d_in[5];
  const float* intr   = (const float*)d_in[6];
  const float* c2w    = (const float*)d_in[7];
  const float* fpose  = (const float*)d_in[8];
  float* out = (float*)d_out;
  float* ws  = (float*)d_ws;

  const int copy_blocks = (int)((RGB_SZ / 4 + 255) / 256) + 1;  // last block zeroes
  hipLaunchKernelGGL(init_k, dim3(copy_blocks), dim3(256), 0, stream,
                     (const float4*)sem, (float4*)(out + OFF_SEM), ws);
  hipLaunchKernelGGL(preprocess_k, dim3(TOT / 256), dim3(256), 0, stream,
                     center, scale, feat, opac, bg, intr, fpose, c2w, ws);
  hipLaunchKernelGGL(raster_k, dim3(NTX, NTY, TV), dim3(64), 0, stream, ws, out);
  hipLaunchKernelGGL(finalize_k, dim3(1), dim3(256), 0, stream, ws, out);
}